// Round 16
// baseline (318.857 us; speedup 1.0000x reference)
//
#include <hip/hip_runtime.h>
#include <hip/hip_bf16.h>
#include <math.h>

// Problem constants (GQA attention block)
#define HID 2048
#define NH 16      // num query heads
#define NKV 4      // kv heads
#define HD 128     // head dim
#define GQ 4       // heads per kv group
#define BATCH 2

typedef short short8v __attribute__((ext_vector_type(8)));
typedef float f32x4 __attribute__((ext_vector_type(4)));

// fp32 -> bf16 round-to-nearest-even
__device__ __forceinline__ ushort f2bf(float f) {
  uint u = __float_as_uint(f);
  uint r = (u + 0x7fffu + ((u >> 16) & 1u)) >> 16;
  return (ushort)r;
}

// packed 2x f32 -> bf16 (RNE), single instruction
__device__ __forceinline__ uint cvt_pk_bf16(float lo, float hi) {
  uint r;
  asm("v_cvt_pk_bf16_f32 %0, %1, %2" : "=v"(r) : "v"(lo), "v"(hi));
  return r;
}

// Async global->LDS DMA, 16 B per lane. LDS dest = wave-uniform base +
// lane*16 (hardware rule); GLOBAL source is per-lane.
__device__ __forceinline__ void gld_lds16(const void* g, void* lds) {
  __builtin_amdgcn_global_load_lds(
      (const __attribute__((address_space(1))) unsigned int*)g,
      (__attribute__((address_space(3))) unsigned int*)lds, 16, 0, 0);
}

// Intra-wave LDS store->load fence (rule #18: sched_barrier after lgkmcnt).
#define WAVE_LDS_FENCE()                                \
  do {                                                  \
    asm volatile("s_waitcnt lgkmcnt(0)" ::: "memory");  \
    __builtin_amdgcn_sched_barrier(0);                  \
  } while (0)

// Work-item table for causal-triangle balancing: item -> (q-tile, k-lo).
__device__ const int QT_TAB[24] = {7, 8, 9, 10, 11, 12, 13, 14, 15, 15, 6, 14,
                                   5, 13, 4, 12, 3, 11, 2, 10, 1, 9, 0, 8};
__device__ const int LO_TAB[24] = {0, 0, 0, 0, 0, 0, 0, 0, 0, 16, 0, 16,
                                   0, 16, 0, 16, 0, 16, 0, 16, 0, 16, 0, 16};

// ---------------------------------------------------------------------------
// Fused prep kernel: castx + 4x tcast (one launch).
// ---------------------------------------------------------------------------
__global__ __launch_bounds__(256) void prep_kernel(
    const float* __restrict__ x, ushort* __restrict__ xb,
    const float* __restrict__ wq, ushort* __restrict__ wqT,
    const float* __restrict__ wk, ushort* __restrict__ wkT,
    const float* __restrict__ wv, ushort* __restrict__ wvT,
    const float* __restrict__ wo, ushort* __restrict__ woT) {
  const int bid = blockIdx.x;
  const int t = threadIdx.x;
  if (bid < 4096) {
    const int i = (bid * 256 + t) * 8;
    float4 f0 = *reinterpret_cast<const float4*>(x + i);
    float4 f1 = *reinterpret_cast<const float4*>(x + i + 4);
    uint4 o;
    o.x = (uint)f2bf(f0.x) | ((uint)f2bf(f0.y) << 16);
    o.y = (uint)f2bf(f0.z) | ((uint)f2bf(f0.w) << 16);
    o.z = (uint)f2bf(f1.x) | ((uint)f2bf(f1.y) << 16);
    o.w = (uint)f2bf(f1.z) | ((uint)f2bf(f1.w) << 16);
    *reinterpret_cast<uint4*>(xb + i) = o;
  } else {
    const float* W;
    ushort* Wt;
    int N, idx;
    if (bid < 8192)       { W = wq; Wt = wqT; N = 2048; idx = bid - 4096; }
    else if (bid < 9216)  { W = wk; Wt = wkT; N = 512;  idx = bid - 8192; }
    else if (bid < 10240) { W = wv; Wt = wvT; N = 512;  idx = bid - 9216; }
    else                  { W = wo; Wt = woT; N = 2048; idx = bid - 10240; }
    const int K = 2048;
    const int k0 = (idx & 63) * 32;
    const int n0 = (idx >> 6) * 32;
    __shared__ float T[32][33];
    const int r = t >> 3;
    const int c4 = (t & 7) * 4;
    float4 vin = *reinterpret_cast<const float4*>(
        &W[(size_t)(k0 + r) * N + n0 + c4]);
    T[c4 + 0][r] = vin.x;
    T[c4 + 1][r] = vin.y;
    T[c4 + 2][r] = vin.z;
    T[c4 + 3][r] = vin.w;
    __syncthreads();
    ushort4 o;
    o.x = f2bf(T[r][c4 + 0]);
    o.y = f2bf(T[r][c4 + 1]);
    o.z = f2bf(T[r][c4 + 2]);
    o.w = f2bf(T[r][c4 + 3]);
    *reinterpret_cast<ushort4*>(&Wt[(size_t)(n0 + r) * K + k0 + c4]) = o;
  }
}

// ---------------------------------------------------------------------------
// merge split-K partials: attnb rows s in [1024, 2048) = (OA+OB)/(LA+LB).
// ---------------------------------------------------------------------------
__global__ __launch_bounds__(256) void merge_kernel(
    const float* __restrict__ OaccA, const float* __restrict__ OaccB,
    const float* __restrict__ LaccA, const float* __restrict__ LaccB,
    ushort* __restrict__ attnb) {
  const int i = (int)blockIdx.x * 256 + (int)threadIdx.x;
  const int d8 = i & 15;
  const int h = (i >> 4) & 15;
  const int r = i >> 8;
  const float invl = 1.0f / (LaccA[r * NH + h] + LaccB[r * NH + h]);
  const size_t off = ((size_t)r * (NH * HD)) + h * HD + d8 * 8;
  float4 a0 = *reinterpret_cast<const float4*>(OaccA + off);
  float4 a1 = *reinterpret_cast<const float4*>(OaccA + off + 4);
  float4 b0 = *reinterpret_cast<const float4*>(OaccB + off);
  float4 b1 = *reinterpret_cast<const float4*>(OaccB + off + 4);
  uint4 o;
  o.x = cvt_pk_bf16((a0.x + b0.x) * invl, (a0.y + b0.y) * invl);
  o.y = cvt_pk_bf16((a0.z + b0.z) * invl, (a0.w + b0.w) * invl);
  o.z = cvt_pk_bf16((a1.x + b1.x) * invl, (a1.y + b1.y) * invl);
  o.w = cvt_pk_bf16((a1.z + b1.z) * invl, (a1.w + b1.w) * invl);
  const int b = r >> 10;
  const int s = 1024 + (r & 1023);
  *reinterpret_cast<uint4*>(
      &attnb[((size_t)(b * 2048 + s)) * (NH * HD) + h * HD + d8 * 8]) = o;
}

// ---------------------------------------------------------------------------
// bf16 MFMA GEMM -- R23: 256x256 tile, BK=64, 512 thr (8 waves, 2Mx4N),
// 4-phase-per-K-tile schedule (guide's 8-phase template, 1 K-tile/iter).
// Per wave: output 128x64 = acc[8][4]; 64 MFMA/K-tile in 4 quadrant-phases
// of 16. Phase = {ds_reads (12/4/12/4) ; stage 1 half-tile (2 gld_lds) ;
// s_barrier ; lgkmcnt(0)+sched_barrier ; setprio(1) 16 MFMA setprio(0) ;
// s_barrier}. Counted vmcnt once per K-tile (phase 3): stage ledger
// t+1 = {(t-1)p3: h0, t p0-p2: h1-h3}; after p3 stages t+2 h0, vmcnt(2)
// drains exactly t+1's 8 loads, keeps t+2 h0 in flight -- never drains.
// LDS 128 KB (2 buf x [A 256x64 | B 256x64] bf16), 1 block/CU (the
// schedule's design point per m201). Chunk-XOR swizzle c^(r&7) applied on
// the GLOBAL source (rule #21: linear DMA dest); frag ds_read_b128 at slot
// (ks*4+quad)^(lr&7) -> banks spread over all 32 (2-way = free).
// Same-buffer staging overlap only at p3 (t+2 h0 vs qi=1 reads): the
// m201-validated race discipline (DMA latency >> lgkmcnt window).
// ---------------------------------------------------------------------------
template <int MODE>
__global__ __launch_bounds__(512, 2) void gemm_big(
    const ushort* __restrict__ A,
    const ushort* __restrict__ W0, const ushort* __restrict__ W1,
    const ushort* __restrict__ W2,
    const float* __restrict__ b0, const float* __restrict__ b1,
    const float* __restrict__ b2,
    void* __restrict__ C0, void* __restrict__ C1, void* __restrict__ C2,
    int M, int K, int S) {
  __shared__ ushort As[2][256 * 64];
  __shared__ ushort Bs[2][256 * 64];
  const int tid = threadIdx.x;

  // XCD-chunked swizzle of flat block id (nwg % 8 == 0 for both grids)
  const int nbx = (int)gridDim.x;
  int bid = (int)blockIdx.y * nbx + (int)blockIdx.x;
  const int cpx = (nbx * (int)gridDim.y) >> 3;
  bid = (bid & 7) * cpx + (bid >> 3);
  const int m0 = (bid / nbx) * 256;
  const int n0 = (bid % nbx) * 256;

  const int wave = tid >> 6;       // 0..7
  const int lane = tid & 63;
  const int quad = lane >> 4;
  const int lr = lane & 15;
  const int wr = wave >> 2;        // 0..1 (M)
  const int wc = wave & 3;         // 0..3 (N)
  const int rloc = lane >> 3;      // 0..7: row within 8-row DMA slice
  const int gc8 = ((lane & 7) ^ rloc) * 8;  // pre-swizzled global col chunk

  // segment select (wave-uniform); 256 divides all segment boundaries
  const ushort* Wt;
  const float* bias;
  int nloc, Nout, om;
  void* Cout;
  if (MODE == 0) {
    Wt = W0; bias = b0; nloc = n0; Nout = 2048; om = 0; Cout = C0;
  } else {
    if (n0 < 2048)      { Wt = W0; bias = b0; nloc = n0;        Nout = 2048; om = 1; Cout = C0; }
    else if (n0 < 2560) { Wt = W1; bias = b1; nloc = n0 - 2048; Nout = 512;  om = 1; Cout = C1; }
    else                { Wt = W2; bias = b2; nloc = n0 - 2560; Nout = 512;  om = 2; Cout = C2; }
  }

  f32x4 acc[8][4];
#pragma unroll
  for (int i = 0; i < 8; ++i)
#pragma unroll
    for (int j = 0; j < 4; ++j) acc[i][j] = (f32x4){0.f, 0.f, 0.f, 0.f};

  const int nt = K / 64;

  // stage half-tile h (0=A rows 0-127, 1=A rows 128-255, 2=B0, 3=B1) of
  // K-tile tt into buffer bf: 2 gld_lds per wave (rows wave*8+rloc, +64).
#define STAGE_HALF(bf, tt, h)                                               \
  do {                                                                      \
    const ushort* s_ = ((h) < 2) ? A : Wt;                                  \
    const int base_ = ((h) < 2) ? m0 : nloc;                                \
    ushort* d_ = ((h) < 2) ? &As[bf][0] : &Bs[bf][0];                       \
    const int hh_ = (h) & 1;                                                \
    gld_lds16(&s_[(size_t)(base_ + hh_ * 128 + wave * 8 + rloc) * K +       \
                  (tt) * 64 + gc8],                                         \
              &d_[hh_ * 8192 + wave * 512]);                                \
    gld_lds16(&s_[(size_t)(base_ + hh_ * 128 + 64 + wave * 8 + rloc) * K +  \
                  (tt) * 64 + gc8],                                         \
              &d_[hh_ * 8192 + 4096 + wave * 512]);                         \
  } while (0)

  // frag loads: A rows wr*128+qi*64+fi*16+lr; B rows wc*64+qj*32+fj*16+lr;
  // slot = (ks*4+quad) ^ (lr&7).
#define LOAD_A(qi)                                                          \
  do {                                                                      \
    _Pragma("unroll") for (int fi = 0; fi < 4; ++fi)                        \
        _Pragma("unroll") for (int ks = 0; ks < 2; ++ks) {                  \
      const int row_ = wr * 128 + (qi)*64 + fi * 16 + lr;                   \
      afr[fi][ks] = *reinterpret_cast<const short8v*>(                      \
          &As[cur][row_ * 64 + (((ks * 4 + quad) ^ (lr & 7))) * 8]);        \
    }                                                                       \
  } while (0)
#define LOAD_B(qj)                                                          \
  do {                                                                      \
    _Pragma("unroll") for (int fj = 0; fj < 2; ++fj)                        \
        _Pragma("unroll") for (int ks = 0; ks < 2; ++ks) {                  \
      const int row_ = wc * 64 + (qj)*32 + fj * 16 + lr;                    \
      bfr[fj][ks] = *reinterpret_cast<const short8v*>(                      \
          &Bs[cur][row_ * 64 + (((ks * 4 + quad) ^ (lr & 7))) * 8]);        \
    }                                                                       \
  } while (0)
#define MFMA_Q(qi, qj)                                                      \
  do {                                                                      \
    __builtin_amdgcn_s_setprio(1);                                          \
    _Pragma("unroll") for (int fi = 0; fi < 4; ++fi)                        \
        _Pragma("unroll") for (int fj = 0; fj < 2; ++fj)                    \
            _Pragma("unroll") for (int ks = 0; ks < 2; ++ks)                \
                acc[(qi)*4 + fi][(qj)*2 + fj] =                             \
        __builtin_amdgcn_mfma_f32_16x16x32_bf16(                            \
            afr[fi][ks], bfr[fj][ks], acc[(qi)*4 + fi][(qj)*2 + fj], 0, 0,  \
            0);                                                             \
    __builtin_amdgcn_s_setprio(0);                                          \
  } while (0)
#define PHASE_SYNC()                                    \
  do {                                                  \
    __builtin_amdgcn_s_barrier();                       \
    asm volatile("s_waitcnt lgkmcnt(0)" ::: "memory");  \
    __builtin_amdgcn_sched_barrier(0);                  \
  } while (0)
#define PHASE_END() __builtin_amdgcn_s_barrier()

  // prologue: tile 0 (4 halves) + tile 1 h0; wait tile 0 (keep 2 in flight)
  STAGE_HALF(0, 0, 0);
  STAGE_HALF(0, 0, 1);
  STAGE_HALF(0, 0, 2);
  STAGE_HALF(0, 0, 3);
  if (nt > 1) {
    STAGE_HALF(1, 1, 0);
    asm volatile("s_waitcnt vmcnt(2)" ::: "memory");
  } else {
    asm volatile("s_waitcnt vmcnt(0)" ::: "memory");
  }
  __builtin_amdgcn_s_barrier();

  for (int t = 0; t < nt; ++t) {
    const int cur = t & 1;
    short8v afr[4][2], bfr[2][2];
    // ---- phase 0: quadrant (0,0) ----
    LOAD_A(0);
    LOAD_B(0);
    if (t + 1 < nt) STAGE_HALF(cur ^ 1, t + 1, 1);
    PHASE_SYNC();
    MFMA_Q(0, 0);
    PHASE_END();
    // ---- phase 1: quadrant (0,1) ----
    LOAD_B(1);
    if (t + 1 < nt) STAGE_HALF(cur ^ 1, t + 1, 2);
    PHASE_SYNC();
    MFMA_Q(0, 1);
    PHASE_END();
    // ---- phase 2: quadrant (1,0) ----
    LOAD_A(1);
    LOAD_B(0);
    if (t + 1 < nt) STAGE_HALF(cur ^ 1, t + 1, 3);
    PHASE_SYNC();
    MFMA_Q(1, 0);
    PHASE_END();
    // ---- phase 3: quadrant (1,1) + K-tile boundary wait ----
    LOAD_B(1);
    if (t + 2 < nt) STAGE_HALF(cur, t + 2, 0);  // m201-style in-use-buffer
                                                // stage; DMA latency >>
                                                // lgkmcnt window
    if (t + 1 < nt) {
      if (t + 2 < nt) {
        asm volatile("s_waitcnt vmcnt(2)" ::: "memory");
      } else {
        asm volatile("s_waitcnt vmcnt(0)" ::: "memory");
      }
    }
    PHASE_SYNC();
    MFMA_Q(1, 1);
    PHASE_END();
  }
#undef STAGE_HALF
#undef LOAD_A
#undef LOAD_B
#undef MFMA_Q
#undef PHASE_SYNC
#undef PHASE_END

  // D layout: row = quad*4+reg, col = lane&15 (verified R5 via output)
#pragma unroll
  for (int i = 0; i < 8; ++i) {
    const int row_base = m0 + wr * 128 + i * 16 + quad * 4;
#pragma unroll
    for (int j = 0; j < 4; ++j) {
      const int col = nloc + wc * 64 + j * 16 + lr;
      const float b = bias[col];
      if (om == 0) {
        float* C = (float*)Cout;
#pragma unroll
        for (int rg = 0; rg < 4; ++rg)
          C[(size_t)(row_base + rg) * Nout + col] = acc[i][j][rg] + b;
      } else if (om == 1) {
        ushort* C = (ushort*)Cout;
#pragma unroll
        for (int rg = 0; rg < 4; ++rg)
          C[(size_t)(row_base + rg) * Nout + col] = f2bf(acc[i][j][rg] + b);
      } else {
        ushort* C = (ushort*)Cout;
        const int bb = (row_base >= S) ? 1 : 0;
        const int s = row_base - bb * S;
        const int kvh = col >> 7;
        const int d = col & 127;
        ushort4 o;
        o.x = f2bf(acc[i][j][0] + b);
        o.y = f2bf(acc[i][j][1] + b);
        o.z = f2bf(acc[i][j][2] + b);
        o.w = f2bf(acc[i][j][3] + b);
        *reinterpret_cast<ushort4*>(
            &C[((size_t)(bb * NKV + kvh) * HD + d) * S + s]) = o;
      }
    }
  }
}

// ---------------------------------------------------------------------------
// Stage one 64-col K tile (16 KB) or V tile (16 KB) via global_load_lds DMA,
// 8 waves x 2 calls. LDS dest LINEAR; XOR swizzle on the GLOBAL source.
// ---------------------------------------------------------------------------
__device__ __forceinline__ void stage_k8(const ushort* __restrict__ Kb,
                                         ushort* Kdst, int k0, int wave,
                                         int lane) {
  const int rK = lane >> 4, cK = lane & 15;
#pragma unroll
  for (int c = 0; c < 2; ++c) {
    const int g = wave * 2 + c;
    const int row = g * 4 + rK;
    const int jk = cK ^ (row & 15);
    gld_lds16(&Kb[(size_t)(k0 + row) * (NKV * HD) + jk * 8], &Kdst[g * 512]);
  }
}
__device__ __forceinline__ void stage_v8(const ushort* __restrict__ Vb,
                                         ushort* Vdst, int k0, int S, int wave,
                                         int lane) {
  const int rV = lane >> 3, cV = lane & 7;
#pragma unroll
  for (int c = 0; c < 2; ++c) {
    const int g = wave * 2 + c;
    const int d = g * 8 + rV;
    const int jv = cV ^ (d & 7);
    gld_lds16(&Vb[(size_t)d * S + k0 + jv * 8], &Vdst[g * 512]);
  }
}

// ---------------------------------------------------------------------------
// MFMA flash attention (causal GQA), all-bf16. (R16 structure, unchanged.)
// ---------------------------------------------------------------------------
__global__ __launch_bounds__(512, 4) void gqa_attn_mfma(
    const ushort* __restrict__ Qg, const ushort* __restrict__ Kgl,
    const ushort* __restrict__ Vt_g, ushort* __restrict__ O,
    float* __restrict__ OaccA, float* __restrict__ OaccB,
    float* __restrict__ LaccA, float* __restrict__ LaccB, int S) {
  __shared__ __align__(16) ushort L[24576];  // 48 KB
  ushort* K0 = L;
  ushort* K1 = L + 8192;
  ushort* Vs = L + 16384;

  const int tid = threadIdx.x;
  const int wave = tid >> 6;
  const int lane = tid & 63;
  const int quad = lane >> 4;
  const int lr = lane & 15;
  const int item = blockIdx.z;
  const int qt = QT_TAB[item];
  const int lo = LO_TAB[item];
  const int ntf = 2 * qt + 2;
  const int hi = lo ? ntf : (ntf < 16 ? ntf : 16);
  const bool part = (qt >= 8);
  const int q0 = qt * 128;
  const int hq = blockIdx.x;
  const int b = blockIdx.y;
  const int kvh = hq >> 2;
  const float C = 0.12751745f;  // (1/sqrt(128)) * log2(e)

  const ushort* Qb = Qg + ((size_t)b * S) * (NH * HD) + (size_t)hq * HD;
  const ushort* Kb = Kgl + ((size_t)b * S) * (NKV * HD) + (size_t)kvh * HD;
  const ushort* Vb = Vt_g + ((size_t)(b * NKV + kvh) * HD) * S;

#pragma unroll
  for (int i = 0; i < 4; ++i) {
    const int id = tid + i * 512;
    const int r = id >> 4, c = id & 15;
    const int p = c ^ (r & 15);
    *reinterpret_cast<uint4*>(&L[r * 128 + p * 8]) =
        *reinterpret_cast<const uint4*>(
            &Qb[(size_t)(q0 + r) * (NH * HD) + c * 8]);
  }
  __syncthreads();
  short8v aq[4];
  {
    const int ra = wave * 16 + lr;
#pragma unroll
    for (int ks = 0; ks < 4; ++ks)
      aq[ks] = *reinterpret_cast<const short8v*>(
          &L[ra * 128 + (((ks * 4 + quad) ^ lr) & 15) * 8]);
  }
  __syncthreads();

  f32x4 oacc[8];
#pragma unroll
  for (int nb = 0; nb < 8; ++nb) oacc[nb] = (f32x4){0.f, 0.f, 0.f, 0.f};
  float l_r = 0.f;

  const int laneA = ((quad * 2) & 3) * 16 + lr;
  const int laneB = ((quad * 2 + 1) & 3) * 16 + lr;
  const bool hihalf = (quad >= 2);

  stage_k8(Kb, (lo & 1) ? K1 : K0, lo * 64, wave, lane);

  for (int kt = lo; kt < hi; ++kt) {
    const int k0v = kt * 64;
    const ushort* Kc = (kt & 1) ? K1 : K0;

    __builtin_amdgcn_s_barrier();
    stage_v8(Vb, Vs, k0v, S, wave, lane);
    if (kt + 1 < hi) {
      stage_k8(Kb, (kt & 1) ? K0 : K1, k0v + 64, wave, lane);
      asm volatile("s_waitcnt vmcnt(4)" ::: "memory");
    } else {
      asm volatile("s_waitcnt vmcnt(2)" ::: "memory");
    }
    __builtin_amdgcn_s_barrier();
    __builtin_amdgcn_sched_barrier(0);

    f32x4 sacc[4];
    __builtin_amdgcn_s_setprio(1);
#pragma unroll
    for (int nb = 0; nb < 4; ++nb) {
      sacc[nb] = (f32x4){0.f, 0.f, 0.f, 0.f};
      const int rb = nb * 16 + lr;
#pragma unroll
      for (int ks = 0; ks < 4; ++ks) {
        short8v bk = *reinterpret_cast<const short8v*>(
            &Kc[rb * 128 + (((ks * 4 + quad) ^ lr) & 15) * 8]);
        sacc[nb] = __builtin_amdgcn_mfma_f32_16x16x32_bf16(
            bk, aq[ks], sacc[nb], 0, 0, 0);
      }
    }
    __builtin_amdgcn_s_setprio(0);

    const bool needmask = (kt >= 2 * qt);
    const int qi = q0 + wave * 16 + lr;
    uint u[4][2];
    float rs = 0.f;
#pragma unroll
    for (int nb = 0; nb < 4; ++nb) {
      float p[4];
#pragma unroll
      for (int rg = 0; rg < 4; ++rg) {
        float sv = sacc[nb][rg] * C;
        if (needmask) {
          const int kj = k0v + nb * 16 + quad * 4 + rg;
          if (kj > qi) sv = -1e30f;
        }
        p[rg] = __builtin_amdgcn_exp2f(sv);
        rs += p[rg];
      }
      u[nb][0] = cvt_pk_bf16(p[0], p[1]);
      u[nb][1] = cvt_pk_bf16(p[2], p[3]);
    }
    rs += __shfl_xor(rs, 16);
    rs += __shfl_xor(rs, 32);
    l_r += rs;

    short8v ap[2];
#pragma unroll
    for (int ks = 0; ks < 2; ++ks) {
      const uint w0a = __shfl(u[2 * ks + 0][0], laneA);
      const uint w0b = __shfl(u[2 * ks + 1][0], laneA);
      const uint w1a = __shfl(u[2 * ks + 0][1], laneA);
      const uint w1b = __shfl(u[2 * ks + 1][1], laneA);
      const uint w2a = __shfl(u[2 * ks + 0][0], laneB);
      const uint w2b = __shfl(u[2 * ks + 1][0], laneB);
      const uint w3a = __shfl(u[2 * ks + 0][1], laneB);
      const uint w3b = __shfl(u[2 * ks + 1][1], laneB);
      uint4 q4;
      q4.x = hihalf ? w0b : w0a;
      q4.y = hihalf ? w1b : w1a;
      q4.z = hihalf ? w2b : w2a;
      q4.w = hihalf ? w3b : w3a;
      ap[ks] = *reinterpret_cast<short8v*>(&q4);
    }

    if (kt + 1 < hi) {
      asm volatile("s_waitcnt vmcnt(2)" ::: "memory");
    } else {
      asm volatile("s_waitcnt vmcnt(0)" ::: "memory");
    }
    __builtin_amdgcn_s_barrier();
    __builtin_amdgcn_sched_barrier(0);

    __builtin_amdgcn_s_setprio(1);
#pragma unroll
    for (int nb = 0; nb < 8; ++nb) {
      const int rv = nb * 16 + lr;
#pragma unroll
      for (int ks = 0; ks < 2; ++ks) {
        short8v bv = *reinterpret_cast<const short8v*>(
            &Vs[rv * 64 + (((ks * 4 + quad) ^ lr) & 7) * 8]);
        oacc[nb] = __builtin_amdgcn_mfma_f32_16x16x32_bf16(
            ap[ks], bv, oacc[nb], 0, 0, 0);
      }
    }
    __builtin_amdgcn_s_setprio(0);
  }

  if (part) {
    float* Oacc = lo ? OaccB : OaccA;
    float* Lacc = lo ? LaccB : LaccA;
    float* Oa = Oacc +
                ((size_t)(b * 1024 + (q0 - 1024) + wave * 16 + quad * 4)) *
                    (NH * HD) +
                hq * HD;
#pragma unroll
    for (int nb = 0; nb < 8; ++nb)
#pragma unroll
      for (int rg = 0; rg < 4; ++rg)
        Oa[(size_t)rg * (NH * HD) + nb * 16 + lr] = oacc[nb][rg];
    if (quad == 0)
      Lacc[(size_t)(b * 1024 + (q0 - 1024) + wave * 16 + lr) * NH + hq] = l_r;
  } else {
    const float invl = 1.0f / l_r;
    float inv[4];
#pragma unroll
    for (int rg = 0; rg < 4; ++rg)
      inv[rg] = __shfl(invl, (lane & 48) | (quad * 4 + rg));
    __syncthreads();
    ushort* ow = &L[wave * 16 * 128];
#pragma unroll
    for (int nb = 0; nb < 8; ++nb)
#pragma unroll
      for (int rg = 0; rg < 4; ++rg)
        ow[(quad * 4 + rg) * 128 + nb * 16 + lr] =
            f2bf(oacc[nb][rg] * inv[rg]);
    WAVE_LDS_FENCE();
    ushort* Ob = O + ((size_t)b * S) * (NH * HD) + (size_t)hq * HD;
#pragma unroll
    for (int ii = 0; ii < 4; ++ii) {
      const int id = lane + ii * 64;
      const int r16 = id >> 4, c = id & 15;
      uint4 val = *reinterpret_cast<const uint4*>(&ow[r16 * 128 + c * 8]);
      *reinterpret_cast<uint4*>(
          &Ob[(size_t)(q0 + wave * 16 + r16) * (NH * HD) + c * 8]) = val;
    }
  }
}

// ---------------------------------------------------------------------------
extern "C" void kernel_launch(void* const* d_in, const int* in_sizes, int n_in,
                              void* d_out, int out_size, void* d_ws,
                              size_t ws_size, hipStream_t stream) {
  const float* x = (const float*)d_in[0];
  const float* wq = (const float*)d_in[1];
  const float* bq = (const float*)d_in[2];
  const float* wk = (const float*)d_in[3];
  const float* bk = (const float*)d_in[4];
  const float* wv = (const float*)d_in[5];
  const float* bv = (const float*)d_in[6];
  const float* wo = (const float*)d_in[7];
  const float* bo = (const float*)d_in[8];
  float* out = (float*)d_out;

  const int M = in_sizes[0] / HID;  // B*S = 4096
  const int S = M / BATCH;          // 2048

  // Workspace (76 MB)
  char* w = (char*)d_ws;
  ushort* xb    = (ushort*)(w + 0);            // 16 MB bf16 [M][2048]
  ushort* qb    = (ushort*)(w + (16u << 20));  // 16 MB bf16 [M][2048]
  ushort* kb    = (ushort*)(w + (32u << 20));  //  4 MB bf16 [M][512]
  ushort* vT    = (ushort*)(w + (36u << 20));  //  4 MB bf16 [B][NKV][HD][S]
  ushort* attnb = (ushort*)(w + (40u << 20));  // 16 MB bf16 [M][2048]
  ushort* wqT   = (ushort*)(w + (56u << 20));  //  8 MB bf16 [2048][2048]
  ushort* wkT   = (ushort*)(w + (64u << 20));  //  2 MB bf16 [512][2048]
  ushort* wvT   = (ushort*)(w + (66u << 20));  //  2 MB bf16 [512][2048]
  ushort* woT   = (ushort*)(w + (68u << 20));  //  8 MB bf16 [2048][2048]
  // Scratch reuse by split-K attention (regions dead post-QKV-GEMM):
  float* OaccA = (float*)(w + 0);            // 16 MB f32 (=xb region)
  float* OaccB = out;                        // 16 MB f32 (out buffer)
  float* LaccA = (float*)(w + (64u << 20));  // 128 KB f32 (=wkT region)
  float* LaccB = (float*)(w + (66u << 20));  // 128 KB f32 (=wvT region)

  // Fused prep: castx + 4 tcasts. 14336 blocks.
  prep_kernel<<<dim3(14336), dim3(256), 0, stream>>>(
      x, xb, wq, wqT, wk, wkT, wv, wvT, wo, woT);

  // Fused QKV projection: 12x16 = 192 blocks (256x256 tiles, 1 block/CU)
  gemm_big<1><<<dim3(3072 / 256, M / 256), dim3(512), 0, stream>>>(
      xb, wqT, wkT, wvT, bq, bk, bv, qb, kb, vT, M, HID, S);

  // MFMA flash attention: 24 LPT-ordered work items per (head, batch)
  gqa_attn_mfma<<<dim3(NH, BATCH, 24), dim3(512), 0, stream>>>(
      qb, kb, vT, attnb, OaccA, OaccB, LaccA, LaccB, S);

  // Merge split-K partials into attnb rows s >= 1024
  merge_kernel<<<dim3(2048), dim3(256), 0, stream>>>(
      OaccA, OaccB, LaccA, LaccB, attnb);

  // Output projection (fp32 out; overwrites the OaccB scratch)
  gemm_big<0><<<dim3(HID / 256, M / 256), dim3(512), 0, stream>>>(
      attnb, woT, nullptr, nullptr, bo, nullptr, nullptr,
      out, nullptr, nullptr, M, HID, S);
}

// Round 17
// 295.184 us; speedup vs baseline: 1.0802x; 1.0802x over previous
//
#include <hip/hip_runtime.h>
#include <hip/hip_bf16.h>
#include <math.h>

// Problem constants (GQA attention block)
#define HID 2048
#define NH 16      // num query heads
#define NKV 4      // kv heads
#define HD 128     // head dim
#define GQ 4       // heads per kv group
#define BATCH 2

typedef short short8v __attribute__((ext_vector_type(8)));
typedef float f32x4 __attribute__((ext_vector_type(4)));

// fp32 -> bf16 round-to-nearest-even
__device__ __forceinline__ ushort f2bf(float f) {
  uint u = __float_as_uint(f);
  uint r = (u + 0x7fffu + ((u >> 16) & 1u)) >> 16;
  return (ushort)r;
}

// packed 2x f32 -> bf16 (RNE), single instruction
__device__ __forceinline__ uint cvt_pk_bf16(float lo, float hi) {
  uint r;
  asm("v_cvt_pk_bf16_f32 %0, %1, %2" : "=v"(r) : "v"(lo), "v"(hi));
  return r;
}

// Async global->LDS DMA, 16 B per lane. LDS dest = wave-uniform base +
// lane*16 (hardware rule). C-style casts emit addrspacecast (flat->AS1/AS3).
__device__ __forceinline__ void gld_lds16(const void* g, void* lds) {
  __builtin_amdgcn_global_load_lds(
      (const __attribute__((address_space(1))) unsigned int*)g,
      (__attribute__((address_space(3))) unsigned int*)lds, 16, 0, 0);
}

// Intra-wave LDS store->load fence (rule #18: sched_barrier after lgkmcnt).
#define WAVE_LDS_FENCE()                                \
  do {                                                  \
    asm volatile("s_waitcnt lgkmcnt(0)" ::: "memory");  \
    __builtin_amdgcn_sched_barrier(0);                  \
  } while (0)

// Work-item table for causal-triangle balancing: item -> (q-tile, k-lo).
// Items sorted by descending tile count; z is the SLOWEST grid dim so long
// items dispatch first (LPT). qt>=8 is split into [0,16) and [16, 2qt+2).
__device__ const int QT_TAB[24] = {7, 8, 9, 10, 11, 12, 13, 14, 15, 15, 6, 14,
                                   5, 13, 4, 12, 3, 11, 2, 10, 1, 9, 0, 8};
__device__ const int LO_TAB[24] = {0, 0, 0, 0, 0, 0, 0, 0, 0, 16, 0, 16,
                                   0, 16, 0, 16, 0, 16, 0, 16, 0, 16, 0, 16};

// ---------------------------------------------------------------------------
// Fused prep kernel: one launch replaces castx + 4x tcast.
// Flat-grid segments (256-thr blocks):
//   [0,     4096): x fp32 -> xb bf16 (8 elems/thread)
//   [4096,  8192): wq  transpose-cast (2048x2048)
//   [8192,  9216): wk  transpose-cast (2048x512)
//   [9216, 10240): wv  transpose-cast (2048x512)
//   [10240,14336): wo  transpose-cast (2048x2048)
// ---------------------------------------------------------------------------
__global__ __launch_bounds__(256) void prep_kernel(
    const float* __restrict__ x, ushort* __restrict__ xb,
    const float* __restrict__ wq, ushort* __restrict__ wqT,
    const float* __restrict__ wk, ushort* __restrict__ wkT,
    const float* __restrict__ wv, ushort* __restrict__ wvT,
    const float* __restrict__ wo, ushort* __restrict__ woT) {
  const int bid = blockIdx.x;
  const int t = threadIdx.x;
  if (bid < 4096) {
    // ---- castx ----
    const int i = (bid * 256 + t) * 8;
    float4 f0 = *reinterpret_cast<const float4*>(x + i);
    float4 f1 = *reinterpret_cast<const float4*>(x + i + 4);
    uint4 o;
    o.x = (uint)f2bf(f0.x) | ((uint)f2bf(f0.y) << 16);
    o.y = (uint)f2bf(f0.z) | ((uint)f2bf(f0.w) << 16);
    o.z = (uint)f2bf(f1.x) | ((uint)f2bf(f1.y) << 16);
    o.w = (uint)f2bf(f1.z) | ((uint)f2bf(f1.w) << 16);
    *reinterpret_cast<uint4*>(xb + i) = o;
  } else {
    // ---- tcast: W fp32 [K][N] -> Wt bf16 [N][K], 32x32 tiles via LDS ----
    const float* W;
    ushort* Wt;
    int N, idx;
    if (bid < 8192)       { W = wq; Wt = wqT; N = 2048; idx = bid - 4096; }
    else if (bid < 9216)  { W = wk; Wt = wkT; N = 512;  idx = bid - 8192; }
    else if (bid < 10240) { W = wv; Wt = wvT; N = 512;  idx = bid - 9216; }
    else                  { W = wo; Wt = woT; N = 2048; idx = bid - 10240; }
    const int K = 2048;  // all weights have K = HID rows
    const int k0 = (idx & 63) * 32;   // 64 k-tiles
    const int n0 = (idx >> 6) * 32;
    __shared__ float T[32][33];
    const int r = t >> 3;          // 0..31
    const int c4 = (t & 7) * 4;    // 0..28
    float4 vin = *reinterpret_cast<const float4*>(
        &W[(size_t)(k0 + r) * N + n0 + c4]);
    T[c4 + 0][r] = vin.x;
    T[c4 + 1][r] = vin.y;
    T[c4 + 2][r] = vin.z;
    T[c4 + 3][r] = vin.w;
    __syncthreads();
    ushort4 o;
    o.x = f2bf(T[r][c4 + 0]);
    o.y = f2bf(T[r][c4 + 1]);
    o.z = f2bf(T[r][c4 + 2]);
    o.w = f2bf(T[r][c4 + 3]);
    *reinterpret_cast<ushort4*>(&Wt[(size_t)(n0 + r) * K + k0 + c4]) = o;
  }
}

// ---------------------------------------------------------------------------
// merge split-K partials: attnb rows s in [1024, 2048) = (OA+OB)/(LA+LB).
// Oacc layout [r][h*128+d], r = b*1024 + (s-1024). 8 f32 -> 8 bf16 / thread.
// ---------------------------------------------------------------------------
__global__ __launch_bounds__(256) void merge_kernel(
    const float* __restrict__ OaccA, const float* __restrict__ OaccB,
    const float* __restrict__ LaccA, const float* __restrict__ LaccB,
    ushort* __restrict__ attnb) {
  const int i = (int)blockIdx.x * 256 + (int)threadIdx.x;  // group of 8
  const int d8 = i & 15;
  const int h = (i >> 4) & 15;
  const int r = i >> 8;  // 0..2047
  const float invl = 1.0f / (LaccA[r * NH + h] + LaccB[r * NH + h]);
  const size_t off = ((size_t)r * (NH * HD)) + h * HD + d8 * 8;
  float4 a0 = *reinterpret_cast<const float4*>(OaccA + off);
  float4 a1 = *reinterpret_cast<const float4*>(OaccA + off + 4);
  float4 b0 = *reinterpret_cast<const float4*>(OaccB + off);
  float4 b1 = *reinterpret_cast<const float4*>(OaccB + off + 4);
  uint4 o;
  o.x = cvt_pk_bf16((a0.x + b0.x) * invl, (a0.y + b0.y) * invl);
  o.y = cvt_pk_bf16((a0.z + b0.z) * invl, (a0.w + b0.w) * invl);
  o.z = cvt_pk_bf16((a1.x + b1.x) * invl, (a1.y + b1.y) * invl);
  o.w = cvt_pk_bf16((a1.z + b1.z) * invl, (a1.w + b1.w) * invl);
  const int b = r >> 10;
  const int s = 1024 + (r & 1023);
  *reinterpret_cast<uint4*>(
      &attnb[((size_t)(b * 2048 + s)) * (NH * HD) + h * HD + d8 * 8]) = o;
}

// ---------------------------------------------------------------------------
// bf16 MFMA GEMM, 128x128 tile, BK=32, 4 waves. Final session config:
// tri-buffered DMA staging (2 tiles in flight, counted vmcnt(8)),
// chunk-XOR LDS swizzle (bank conflicts = 0, rule #21), XCD-chunked +
// L2-blocked tile order. Measured ceiling of the 2-barrier structure
// (~68 us/dispatch); 256^2 deep-pipeline ports regressed twice (R21/R23).
// ---------------------------------------------------------------------------
template <int MODE>
__global__ __launch_bounds__(256) void gemm_big(
    const ushort* __restrict__ A,
    const ushort* __restrict__ W0, const ushort* __restrict__ W1,
    const ushort* __restrict__ W2,
    const float* __restrict__ b0, const float* __restrict__ b1,
    const float* __restrict__ b2,
    void* __restrict__ C0, void* __restrict__ C1, void* __restrict__ C2,
    int M, int K, int S) {
  __shared__ ushort As[3][128 * 32];
  __shared__ ushort Bs[3][128 * 32];
  const int tid = threadIdx.x;

  // XCD-chunked swizzle + L2-blocked within-chunk order (nwg % 8 == 0).
  const int nbx = (int)gridDim.x;
  const int bid0 = (int)blockIdx.y * nbx + (int)blockIdx.x;
  const int cpx = (nbx * (int)gridDim.y) >> 3;
  const int xcd = bid0 & 7;
  const int ic = bid0 >> 3;            // 0..cpx-1
  const int rows = cpx / nbx;          // m-rows per XCD chunk
  const int GN = (nbx < 8) ? nbx : 8;  // n-group width (4 MB of W in L2)
  const int per_g = GN * rows;
  const int g = ic / per_g;
  const int rem = ic - g * per_g;
  const int r_m = rem / GN;
  const int nn = rem - r_m * GN;
  const int m0 = (xcd * rows + r_m) * 128;
  const int n0 = (g * GN + nn) * 128;

  const int wave = tid >> 6;
  const int lane = tid & 63;
  const int quad = lane >> 4;
  const int lr = lane & 15;
  const int l4 = lane >> 2;       // 0..15: row within 16-row DMA group
  // stage col: global chunk = slot ^ ((row>>1)&3) (inverse of read swizzle)
  const int lcs = ((lane & 3) ^ ((lane >> 3) & 3)) * 8;
  // read col slot: quad ^ ((lr>>1)&3) (row-independent: row base = 0 mod 16)
  const int cswz = (quad ^ ((lr >> 1) & 3)) * 8;
  const int wm = (wave >> 1) * 64;
  const int wn = (wave & 1) * 64;

  // segment select (wave-uniform)
  const ushort* Wt;
  const float* bias;
  int nloc, Nout, om;
  void* Cout;
  if (MODE == 0) {
    Wt = W0; bias = b0; nloc = n0; Nout = 2048; om = 0; Cout = C0;
  } else {
    if (n0 < 2048)      { Wt = W0; bias = b0; nloc = n0;        Nout = 2048; om = 1; Cout = C0; }
    else if (n0 < 2560) { Wt = W1; bias = b1; nloc = n0 - 2048; Nout = 512;  om = 1; Cout = C1; }
    else                { Wt = W2; bias = b2; nloc = n0 - 2560; Nout = 512;  om = 2; Cout = C2; }
  }

  f32x4 acc[4][4];
#pragma unroll
  for (int i = 0; i < 4; ++i)
#pragma unroll
    for (int j = 0; j < 4; ++j) acc[i][j] = (f32x4){0.f, 0.f, 0.f, 0.f};

  const size_t rowA = (size_t)(m0 + wave * 32 + l4) * K + lcs;
  const size_t rowB = (size_t)(nloc + wave * 32 + l4) * K + lcs;

  // stage tile t (K-offset t*32) into buffer bi: 4 DMAs per wave
#define STAGE_GEMM(t, bi)                                                  \
  do {                                                                     \
    const int kof = (t) * 32;                                              \
    gld_lds16(&A[rowA + kof], &As[bi][(wave * 32) * 32]);                  \
    gld_lds16(&A[rowA + 16 * K + kof], &As[bi][(wave * 32 + 16) * 32]);    \
    gld_lds16(&Wt[rowB + kof], &Bs[bi][(wave * 32) * 32]);                 \
    gld_lds16(&Wt[rowB + 16 * K + kof], &Bs[bi][(wave * 32 + 16) * 32]);   \
  } while (0)

  const int nt = K / 32;
  STAGE_GEMM(0, 0);
  STAGE_GEMM(1, 1);

  for (int t = 0; t < nt; ++t) {
    const int cur = t % 3;
    __builtin_amdgcn_s_barrier();  // all waves done reading buf[(t+2)%3]
    if (t + 2 < nt) {
      STAGE_GEMM(t + 2, (t + 2) % 3);
      // 12 outstanding DMAs/wave (t, t+1, t+2); drain oldest 4 (tile t)
      asm volatile("s_waitcnt vmcnt(8)" ::: "memory");
    } else if (t + 1 < nt) {
      asm volatile("s_waitcnt vmcnt(4)" ::: "memory");
    } else {
      asm volatile("s_waitcnt vmcnt(0)" ::: "memory");
    }
    __builtin_amdgcn_s_barrier();  // tile t resident + visible to all waves
    __builtin_amdgcn_sched_barrier(0);

    short8v af[4], bf[4];
#pragma unroll
    for (int x = 0; x < 4; ++x) {
      const int ra = wm + x * 16 + lr;
      af[x] = *reinterpret_cast<const short8v*>(&As[cur][ra * 32 + cswz]);
      const int rb = wn + x * 16 + lr;
      bf[x] = *reinterpret_cast<const short8v*>(&Bs[cur][rb * 32 + cswz]);
    }
#pragma unroll
    for (int i = 0; i < 4; ++i)
#pragma unroll
      for (int j = 0; j < 4; ++j)
        acc[i][j] = __builtin_amdgcn_mfma_f32_16x16x32_bf16(
            af[i], bf[j], acc[i][j], 0, 0, 0);
  }
#undef STAGE_GEMM

  // D layout: row = quad*4+reg, col = lane&15 (verified R5 via output)
#pragma unroll
  for (int i = 0; i < 4; ++i) {
    const int row_base = m0 + wm + i * 16 + quad * 4;
#pragma unroll
    for (int j = 0; j < 4; ++j) {
      const int col = nloc + wn + j * 16 + lr;
      const float b = bias[col];
      if (om == 0) {
        float* C = (float*)Cout;
#pragma unroll
        for (int rg = 0; rg < 4; ++rg)
          C[(size_t)(row_base + rg) * Nout + col] = acc[i][j][rg] + b;
      } else if (om == 1) {
        ushort* C = (ushort*)Cout;
#pragma unroll
        for (int rg = 0; rg < 4; ++rg)
          C[(size_t)(row_base + rg) * Nout + col] = f2bf(acc[i][j][rg] + b);
      } else {
        ushort* C = (ushort*)Cout;
        const int bb = (row_base >= S) ? 1 : 0;
        const int s = row_base - bb * S;
        const int kvh = col >> 7;
        const int d = col & 127;
        ushort4 o;
        o.x = f2bf(acc[i][j][0] + b);
        o.y = f2bf(acc[i][j][1] + b);
        o.z = f2bf(acc[i][j][2] + b);
        o.w = f2bf(acc[i][j][3] + b);
        *reinterpret_cast<ushort4*>(
            &C[((size_t)(bb * NKV + kvh) * HD + d) * S + s]) = o;
      }
    }
  }
}

// ---------------------------------------------------------------------------
// Stage one 64-col K tile (16 KB) or V tile (16 KB) via global_load_lds DMA,
// 8 waves x 2 calls. LDS dest LINEAR; XOR swizzle applied to the GLOBAL
// source column so resident layout == compute layout (rule #21).
// ---------------------------------------------------------------------------
__device__ __forceinline__ void stage_k8(const ushort* __restrict__ Kb,
                                         ushort* Kdst, int k0, int wave,
                                         int lane) {
  const int rK = lane >> 4, cK = lane & 15;  // 4 rows x 16 chunks / call
#pragma unroll
  for (int c = 0; c < 2; ++c) {
    const int g = wave * 2 + c;  // 0..15
    const int row = g * 4 + rK;
    const int jk = cK ^ (row & 15);
    gld_lds16(&Kb[(size_t)(k0 + row) * (NKV * HD) + jk * 8], &Kdst[g * 512]);
  }
}
__device__ __forceinline__ void stage_v8(const ushort* __restrict__ Vb,
                                         ushort* Vdst, int k0, int S, int wave,
                                         int lane) {
  const int rV = lane >> 3, cV = lane & 7;  // 8 rows x 8 chunks / call
#pragma unroll
  for (int c = 0; c < 2; ++c) {
    const int g = wave * 2 + c;  // 0..15
    const int d = g * 8 + rV;
    const int jv = cV ^ (d & 7);
    gld_lds16(&Vb[(size_t)d * S + k0 + jv * 8], &Vdst[g * 512]);
  }
}

// ---------------------------------------------------------------------------
// MFMA flash attention (causal GQA), all-bf16. (R16 structure, session
// final: 48 KB LDS, K dbuf + V single-buffered, counted vmcnt, swapped
// QK^T, fixed-max exp2 softmax, shuffle P relayout, atomic-free split-K
// with chunk-exclusive plain-store buffers, launch_bounds(512,4).)
// ---------------------------------------------------------------------------
__global__ __launch_bounds__(512, 4) void gqa_attn_mfma(
    const ushort* __restrict__ Qg, const ushort* __restrict__ Kgl,
    const ushort* __restrict__ Vt_g, ushort* __restrict__ O,
    float* __restrict__ OaccA, float* __restrict__ OaccB,
    float* __restrict__ LaccA, float* __restrict__ LaccB, int S) {
  // L (ushorts): [0:8192) K0 | [8192:16384) K1 | [16384:24576) V (single).
  // Pre-loop: L[0:16384) = Q staging. Post-loop: L[0:16384) = out staging.
  __shared__ __align__(16) ushort L[24576];  // 48 KB
  ushort* K0 = L;
  ushort* K1 = L + 8192;
  ushort* Vs = L + 16384;

  const int tid = threadIdx.x;
  const int wave = tid >> 6;   // 0..7
  const int lane = tid & 63;
  const int quad = lane >> 4;
  const int lr = lane & 15;
  const int item = blockIdx.z;
  const int qt = QT_TAB[item];
  const int lo = LO_TAB[item];
  const int ntf = 2 * qt + 2;                    // full tile count for qt
  const int hi = lo ? ntf : (ntf < 16 ? ntf : 16);
  const bool part = (qt >= 8);
  const int q0 = qt * 128;
  const int hq = blockIdx.x;
  const int b = blockIdx.y;
  const int kvh = hq >> 2;
  const float C = 0.12751745f;  // (1/sqrt(128)) * log2(e)

  const ushort* Qb = Qg + ((size_t)b * S) * (NH * HD) + (size_t)hq * HD;
  const ushort* Kb = Kgl + ((size_t)b * S) * (NKV * HD) + (size_t)kvh * HD;
  const ushort* Vb = Vt_g + ((size_t)(b * NKV + kvh) * HD) * S;

  // ---- stage Q (128 rows) through L[0:16384), hoist A-frags to regs ----
#pragma unroll
  for (int i = 0; i < 4; ++i) {
    const int id = tid + i * 512;
    const int r = id >> 4, c = id & 15;
    const int p = c ^ (r & 15);
    *reinterpret_cast<uint4*>(&L[r * 128 + p * 8]) =
        *reinterpret_cast<const uint4*>(
            &Qb[(size_t)(q0 + r) * (NH * HD) + c * 8]);
  }
  __syncthreads();
  short8v aq[4];
  {
    const int ra = wave * 16 + lr;
#pragma unroll
    for (int ks = 0; ks < 4; ++ks)
      aq[ks] = *reinterpret_cast<const short8v*>(
          &L[ra * 128 + (((ks * 4 + quad) ^ lr) & 15) * 8]);
  }
  __syncthreads();  // all waves done reading Q before any DMA overwrites
                    // (also drains vmcnt -> DMA counting below starts at 0)

  f32x4 oacc[8];
#pragma unroll
  for (int nb = 0; nb < 8; ++nb) oacc[nb] = (f32x4){0.f, 0.f, 0.f, 0.f};
  float l_r = 0.f;  // running sum for q = q0 + wave*16 + lr (fixed max = 0)

  // shuffle sources for P relayout (loop-invariant)
  const int laneA = ((quad * 2) & 3) * 16 + lr;
  const int laneB = ((quad * 2 + 1) & 3) * 16 + lr;
  const bool hihalf = (quad >= 2);

  // ---- prologue: issue K DMA for tile `lo` (2/wave) ----
  stage_k8(Kb, (lo & 1) ? K1 : K0, lo * 64, wave, lane);

  for (int kt = lo; kt < hi; ++kt) {
    const int k0v = kt * 64;
    const ushort* Kc = (kt & 1) ? K1 : K0;

    __builtin_amdgcn_s_barrier();  // PV(kt-1) V-reads + QK(kt-1) K-reads done
    stage_v8(Vb, Vs, k0v, S, wave, lane);  // V(kt): 2 DMAs/wave
    if (kt + 1 < hi) {
      stage_k8(Kb, (kt & 1) ? K0 : K1, k0v + 64, wave, lane);  // K(kt+1)
      // queue: K(kt)=2, V(kt)=2, K(kt+1)=2 -> drain oldest 2 (K(kt))
      asm volatile("s_waitcnt vmcnt(4)" ::: "memory");
    } else {
      // queue: K(kt)=2, V(kt)=2 -> drain K(kt)
      asm volatile("s_waitcnt vmcnt(2)" ::: "memory");
    }
    __builtin_amdgcn_s_barrier();  // K(kt) resident for all waves
    __builtin_amdgcn_sched_barrier(0);

    // ---- QK^T, SWAPPED: D[k][q] (A = K rows, B = Q rows) ----
    f32x4 sacc[4];
    __builtin_amdgcn_s_setprio(1);
#pragma unroll
    for (int nb = 0; nb < 4; ++nb) {
      sacc[nb] = (f32x4){0.f, 0.f, 0.f, 0.f};
      const int rb = nb * 16 + lr;
#pragma unroll
      for (int ks = 0; ks < 4; ++ks) {
        short8v bk = *reinterpret_cast<const short8v*>(
            &Kc[rb * 128 + (((ks * 4 + quad) ^ lr) & 15) * 8]);
        sacc[nb] = __builtin_amdgcn_mfma_f32_16x16x32_bf16(
            bk, aq[ks], sacc[nb], 0, 0, 0);
      }
    }
    __builtin_amdgcn_s_setprio(0);

    // ---- softmax (fixed max 0): lane owns 16 k of q = q0+wave*16+lr ----
    const bool needmask = (kt >= 2 * qt);  // last 2 k-tiles of full range
    const int qi = q0 + wave * 16 + lr;
    uint u[4][2];  // bf16-pair packed P
    float rs = 0.f;
#pragma unroll
    for (int nb = 0; nb < 4; ++nb) {
      float p[4];
#pragma unroll
      for (int rg = 0; rg < 4; ++rg) {
        float sv = sacc[nb][rg] * C;
        if (needmask) {
          const int kj = k0v + nb * 16 + quad * 4 + rg;
          if (kj > qi) sv = -1e30f;
        }
        p[rg] = __builtin_amdgcn_exp2f(sv);
        rs += p[rg];
      }
      u[nb][0] = cvt_pk_bf16(p[0], p[1]);
      u[nb][1] = cvt_pk_bf16(p[2], p[3]);
    }
    rs += __shfl_xor(rs, 16);
    rs += __shfl_xor(rs, 32);
    l_r += rs;

    // ---- P relayout via cross-lane shuffles (no LDS) ----
    short8v ap[2];
#pragma unroll
    for (int ks = 0; ks < 2; ++ks) {
      const uint w0a = __shfl(u[2 * ks + 0][0], laneA);
      const uint w0b = __shfl(u[2 * ks + 1][0], laneA);
      const uint w1a = __shfl(u[2 * ks + 0][1], laneA);
      const uint w1b = __shfl(u[2 * ks + 1][1], laneA);
      const uint w2a = __shfl(u[2 * ks + 0][0], laneB);
      const uint w2b = __shfl(u[2 * ks + 1][0], laneB);
      const uint w3a = __shfl(u[2 * ks + 0][1], laneB);
      const uint w3b = __shfl(u[2 * ks + 1][1], laneB);
      uint4 q4;
      q4.x = hihalf ? w0b : w0a;
      q4.y = hihalf ? w1b : w1a;
      q4.z = hihalf ? w2b : w2a;
      q4.w = hihalf ? w3b : w3a;
      ap[ks] = *reinterpret_cast<short8v*>(&q4);
    }

    // ---- wait V(kt) resident, then PV ----
    if (kt + 1 < hi) {
      // outstanding: V(kt)=2, K(kt+1)=2 -> drain V(kt), keep K(kt+1)
      asm volatile("s_waitcnt vmcnt(2)" ::: "memory");
    } else {
      asm volatile("s_waitcnt vmcnt(0)" ::: "memory");
    }
    __builtin_amdgcn_s_barrier();  // V(kt) resident for all waves
    __builtin_amdgcn_sched_barrier(0);

    __builtin_amdgcn_s_setprio(1);
#pragma unroll
    for (int nb = 0; nb < 8; ++nb) {
      const int rv = nb * 16 + lr;
#pragma unroll
      for (int ks = 0; ks < 2; ++ks) {
        short8v bv = *reinterpret_cast<const short8v*>(
            &Vs[rv * 64 + (((ks * 4 + quad) ^ lr) & 7) * 8]);
        oacc[nb] = __builtin_amdgcn_mfma_f32_16x16x32_bf16(
            ap[ks], bv, oacc[nb], 0, 0, 0);
      }
    }
    __builtin_amdgcn_s_setprio(0);
  }

  if (part) {
    // ---- split path: PLAIN f32 partial stores (chunk-exclusive buffer) ----
    float* Oacc = lo ? OaccB : OaccA;
    float* Lacc = lo ? LaccB : LaccA;
    float* Oa = Oacc +
                ((size_t)(b * 1024 + (q0 - 1024) + wave * 16 + quad * 4)) *
                    (NH * HD) +
                hq * HD;
#pragma unroll
    for (int nb = 0; nb < 8; ++nb)
#pragma unroll
      for (int rg = 0; rg < 4; ++rg)
        Oa[(size_t)rg * (NH * HD) + nb * 16 + lr] = oacc[nb][rg];
    if (quad == 0)
      Lacc[(size_t)(b * 1024 + (q0 - 1024) + wave * 16 + lr) * NH + hq] = l_r;
  } else {
    // ---- direct path: normalize and write attnb (LDS-staged, coalesced) --
    const float invl = 1.0f / l_r;
    float inv[4];
#pragma unroll
    for (int rg = 0; rg < 4; ++rg)
      inv[rg] = __shfl(invl, (lane & 48) | (quad * 4 + rg));
    __syncthreads();  // all waves out of the K-loop before scratch writes
    ushort* ow = &L[wave * 16 * 128];
#pragma unroll
    for (int nb = 0; nb < 8; ++nb)
#pragma unroll
      for (int rg = 0; rg < 4; ++rg)
        ow[(quad * 4 + rg) * 128 + nb * 16 + lr] =
            f2bf(oacc[nb][rg] * inv[rg]);
    WAVE_LDS_FENCE();  // intra-wave: stores -> uint4 readback
    ushort* Ob = O + ((size_t)b * S) * (NH * HD) + (size_t)hq * HD;
#pragma unroll
    for (int ii = 0; ii < 4; ++ii) {
      const int id = lane + ii * 64;
      const int r16 = id >> 4, c = id & 15;
      uint4 val = *reinterpret_cast<const uint4*>(&ow[r16 * 128 + c * 8]);
      *reinterpret_cast<uint4*>(
          &Ob[(size_t)(q0 + wave * 16 + r16) * (NH * HD) + c * 8]) = val;
    }
  }
}

// ---------------------------------------------------------------------------
extern "C" void kernel_launch(void* const* d_in, const int* in_sizes, int n_in,
                              void* d_out, int out_size, void* d_ws,
                              size_t ws_size, hipStream_t stream) {
  const float* x = (const float*)d_in[0];
  const float* wq = (const float*)d_in[1];
  const float* bq = (const float*)d_in[2];
  const float* wk = (const float*)d_in[3];
  const float* bk = (const float*)d_in[4];
  const float* wv = (const float*)d_in[5];
  const float* bv = (const float*)d_in[6];
  const float* wo = (const float*)d_in[7];
  const float* bo = (const float*)d_in[8];
  float* out = (float*)d_out;

  const int M = in_sizes[0] / HID;  // B*S = 4096
  const int S = M / BATCH;          // 2048

  // Workspace (76 MB)
  char* w = (char*)d_ws;
  ushort* xb    = (ushort*)(w + 0);            // 16 MB bf16 [M][2048]
  ushort* qb    = (ushort*)(w + (16u << 20));  // 16 MB bf16 [M][2048]
  ushort* kb    = (ushort*)(w + (32u << 20));  //  4 MB bf16 [M][512]
  ushort* vT    = (ushort*)(w + (36u << 20));  //  4 MB bf16 [B][NKV][HD][S]
  ushort* attnb = (ushort*)(w + (40u << 20));  // 16 MB bf16 [M][2048]
  ushort* wqT   = (ushort*)(w + (56u << 20));  //  8 MB bf16 [2048][2048]
  ushort* wkT   = (ushort*)(w + (64u << 20));  //  2 MB bf16 [512][2048]
  ushort* wvT   = (ushort*)(w + (66u << 20));  //  2 MB bf16 [512][2048]
  ushort* woT   = (ushort*)(w + (68u << 20));  //  8 MB bf16 [2048][2048]
  // Scratch reuse by split-K attention (regions dead post-QKV-GEMM):
  float* OaccA = (float*)(w + 0);            // 16 MB f32 (=xb region)
  float* OaccB = out;                        // 16 MB f32 (out, overwritten by
                                             // the final GEMM afterwards)
  float* LaccA = (float*)(w + (64u << 20));  // 128 KB f32 (=wkT region)
  float* LaccB = (float*)(w + (66u << 20));  // 128 KB f32 (=wvT region)

  // Fused prep: castx + 4 tcasts. 14336 blocks.
  prep_kernel<<<dim3(14336), dim3(256), 0, stream>>>(
      x, xb, wq, wqT, wk, wkT, wv, wvT, wo, woT);

  // Fused QKV projection: 24x32 = 768 blocks (3 blocks/CU, fully resident)
  gemm_big<1><<<dim3(3072 / 128, M / 128), dim3(256), 0, stream>>>(
      xb, wqT, wkT, wvT, bq, bk, bv, qb, kb, vT, M, HID, S);

  // MFMA flash attention: 24 LPT-ordered work items per (head, batch)
  gqa_attn_mfma<<<dim3(NH, BATCH, 24), dim3(512), 0, stream>>>(
      qb, kb, vT, attnb, OaccA, OaccB, LaccA, LaccB, S);

  // Merge split-K partials into attnb rows s >= 1024
  merge_kernel<<<dim3(2048), dim3(256), 0, stream>>>(
      OaccA, OaccB, LaccA, LaccB, attnb);

  // Output projection (fp32 out; overwrites the OaccB scratch)
  gemm_big<0><<<dim3(HID / 128, M / 128), dim3(256), 0, stream>>>(
      attnb, woT, nullptr, nullptr, bo, nullptr, nullptr,
      out, nullptr, nullptr, M, HID, S);
}